// Round 4
// baseline (360.061 us; speedup 1.0000x reference)
//
#include <hip/hip_runtime.h>
#include <hip/hip_bf16.h>

#define BB 4
#define TT 2048
#define DD 1024
#define HH 16

typedef __bf16 bf16;
typedef __bf16 bf16x8 __attribute__((ext_vector_type(8)));
typedef __bf16 bf16x4 __attribute__((ext_vector_type(4)));
typedef float f32x4 __attribute__((ext_vector_type(4)));

#define MFMA16(a, b, c) __builtin_amdgcn_mfma_f32_16x16x32_bf16(a, b, c, 0, 0, 0)

// softmax scale folded into Q at projection: (1/sqrt(64)) * log2(e)
#define C1 0.18033688011112042f

static __device__ inline bf16x8 cvt8(const float* __restrict__ p) {
    const f32x4 a = *reinterpret_cast<const f32x4*>(p);
    const f32x4 b = *reinterpret_cast<const f32x4*>(p + 4);
    bf16x8 r;
    r[0] = (bf16)a[0]; r[1] = (bf16)a[1]; r[2] = (bf16)a[2]; r[3] = (bf16)a[3];
    r[4] = (bf16)b[0]; r[5] = (bf16)b[1]; r[6] = (bf16)b[2]; r[7] = (bf16)b[3];
    return r;
}

// ---------------- Kernel 0: Wout fp32 -> bf16 ----------------
__global__ __launch_bounds__(256) void k_cvt(const float* __restrict__ a, bf16* __restrict__ o, int n) {
    int i = (blockIdx.x * 256 + threadIdx.x) * 4;
    if (i + 3 < n) {
        f32x4 v = *reinterpret_cast<const f32x4*>(a + i);
        bf16x4 r;
        r[0] = (bf16)v[0]; r[1] = (bf16)v[1]; r[2] = (bf16)v[2]; r[3] = (bf16)v[3];
        *reinterpret_cast<bf16x4*>(o + i) = r;
    }
}

// ---------------- Kernel 1: QKV projection ----------------
// Q (pre-scaled by C1), K -> (B*H, T, 64) bf16 ; V -> transposed (B*H, 64, T) bf16
__global__ __launch_bounds__(256) void k_qkv(const float* __restrict__ x,
                                             const float* __restrict__ Wq,
                                             const float* __restrict__ Wk,
                                             const float* __restrict__ Wv,
                                             bf16* __restrict__ Qb,
                                             bf16* __restrict__ Kb,
                                             bf16* __restrict__ VT) {
    __shared__ bf16 vlds[4][64 * 40];
    const int w = threadIdx.x >> 6, lane = threadIdx.x & 63;
    const int c = lane & 15, g = lane >> 4;
    const int bh = blockIdx.y;
    const int b = bh >> 4, h = bh & 15;
    const int tb = blockIdx.x * 128 + w * 32;

    bf16x8 a[2][2];
#pragma unroll
    for (int s = 0; s < 2; s++)
#pragma unroll
        for (int dt = 0; dt < 2; dt++)
            a[s][dt] = cvt8(x + (size_t)(b * TT + tb + 16 * s + c) * DD + h * 64 + 32 * dt + 8 * g);

    const float* const Ws[3] = {Wq, Wk, Wv};
    f32x4 acc[3][2][4];
#pragma unroll
    for (int m = 0; m < 3; m++)
#pragma unroll
        for (int s = 0; s < 2; s++)
#pragma unroll
            for (int e = 0; e < 4; e++)
#pragma unroll
                for (int r = 0; r < 4; r++) acc[m][s][e][r] = 0.0f;

#pragma unroll
    for (int m = 0; m < 3; m++) {
#pragma unroll
        for (int eg = 0; eg < 4; eg++) {
#pragma unroll
            for (int dt = 0; dt < 2; dt++) {
                bf16x8 bf = cvt8(Ws[m] + (size_t)(h * 64 + 16 * eg + c) * 64 + 32 * dt + 8 * g);
#pragma unroll
                for (int s = 0; s < 2; s++)
                    acc[m][s][eg] = MFMA16(a[s][dt], bf, acc[m][s][eg]);
            }
        }
    }

    // store Q (scaled), K (row = t, col = e)
    bf16* const outs[2] = {Qb, Kb};
#pragma unroll
    for (int m = 0; m < 2; m++)
#pragma unroll
        for (int s = 0; s < 2; s++)
#pragma unroll
            for (int eg = 0; eg < 4; eg++)
#pragma unroll
                for (int r = 0; r < 4; r++) {
                    int t = tb + 16 * s + 4 * g + r;
                    float sv = acc[m][s][eg][r];
                    if (m == 0) sv *= C1;
                    outs[m][((size_t)bh * TT + t) * 64 + 16 * eg + c] = (bf16)sv;
                }

    // V: transpose via per-wave LDS tile [64 e][40 t_local]
    bf16* vl = vlds[w];
#pragma unroll
    for (int s = 0; s < 2; s++)
#pragma unroll
        for (int eg = 0; eg < 4; eg++) {
            bf16x4 v4;
#pragma unroll
            for (int r = 0; r < 4; r++) v4[r] = (bf16)acc[2][s][eg][r];
            *reinterpret_cast<bf16x4*>(&vl[(16 * eg + c) * 40 + 16 * s + 4 * g]) = v4;
        }
#pragma unroll
    for (int j = 0; j < 4; j++) {
        bf16x8 v = *reinterpret_cast<bf16x8*>(&vl[lane * 40 + 8 * j]);
        *reinterpret_cast<bf16x8*>(&VT[((size_t)bh * 64 + lane) * TT + tb + 8 * j]) = v;
    }
}

// ---------------- Kernel 2: flash attention (max-free, software-pipelined) ----------------
// Per half-iteration on tile T (SFC = S[T] regs, SFN gets S[T+1], PL = P-LDS buffer for T):
//   exp2+store P[T] -> QK^T[T+1] -> K[T+2] prefetch -> PV[T] -> V[T+1] prefetch
// The QK^T MFMAs cover the P-write lgkm latency; exp2 (VALU) overlaps MFMA across phases.
#define PSTR 76
#define ATTN_STEP(SFC, SFN, PL, T)                                                                   \
    do {                                                                                             \
        _Pragma("unroll") for (int s = 0; s < 2; s++)                                                \
            _Pragma("unroll") for (int kg = 0; kg < 4; kg++)                                         \
                _Pragma("unroll") for (int r = 0; r < 4; r++)                                        \
                    (PL)[(16 * s + 4 * g + r) * PSTR + 16 * kg + c] = (bf16)exp2f(SFC[s][kg][r]);    \
        _Pragma("unroll") for (int s = 0; s < 2; s++)                                                \
            _Pragma("unroll") for (int kg = 0; kg < 4; kg++)                                         \
                _Pragma("unroll") for (int r = 0; r < 4; r++) SFN[s][kg][r] = 0.0f;                  \
        __builtin_amdgcn_s_setprio(1);                                                               \
        _Pragma("unroll") for (int kg = 0; kg < 4; kg++)                                             \
            _Pragma("unroll") for (int dt = 0; dt < 2; dt++)                                         \
                _Pragma("unroll") for (int s = 0; s < 2; s++)                                        \
                    SFN[s][kg] = MFMA16(aq[s][dt], kf[kg * 2 + dt], SFN[s][kg]);                     \
        __builtin_amdgcn_s_setprio(0);                                                               \
        {                                                                                            \
            const int kb2 = (((T) + 2) * 64) & (TT - 1);                                             \
            _Pragma("unroll") for (int kg = 0; kg < 4; kg++)                                         \
                _Pragma("unroll") for (int dt = 0; dt < 2; dt++)                                     \
                    kf[kg * 2 + dt] = *reinterpret_cast<const bf16x8*>(                              \
                        Kh + (size_t)(kb2 + 16 * kg + c) * 64 + 32 * dt + 8 * g);                    \
        }                                                                                            \
        __builtin_amdgcn_s_setprio(1);                                                               \
        _Pragma("unroll") for (int kt = 0; kt < 2; kt++) {                                           \
            bf16x8 pa[2];                                                                            \
            _Pragma("unroll") for (int s = 0; s < 2; s++)                                            \
                pa[s] = *reinterpret_cast<const bf16x8*>((PL) + (16 * s + c) * PSTR + 32 * kt + 8 * g); \
            _Pragma("unroll") for (int dg = 0; dg < 4; dg++)                                         \
                _Pragma("unroll") for (int s = 0; s < 2; s++)                                        \
                    o[s][dg] = MFMA16(pa[s], vf[dg * 2 + kt], o[s][dg]);                             \
            _Pragma("unroll") for (int s = 0; s < 2; s++)                                            \
                lacc[s] = MFMA16(pa[s], onesf, lacc[s]);                                             \
        }                                                                                            \
        __builtin_amdgcn_s_setprio(0);                                                               \
        {                                                                                            \
            const int kb1 = (((T) + 1) * 64) & (TT - 1);                                             \
            _Pragma("unroll") for (int dg = 0; dg < 4; dg++)                                         \
                _Pragma("unroll") for (int kt = 0; kt < 2; kt++)                                     \
                    vf[dg * 2 + kt] = *reinterpret_cast<const bf16x8*>(                              \
                        Vh + (size_t)(16 * dg + c) * TT + kb1 + 32 * kt + 8 * g);                    \
        }                                                                                            \
    } while (0)

__global__ __launch_bounds__(256, 2) void k_attn(const bf16* __restrict__ Qb,
                                                 const bf16* __restrict__ Kb,
                                                 const bf16* __restrict__ VT,
                                                 bf16* __restrict__ AO) {
    __shared__ bf16 plds[4][2][32 * PSTR];
    const int w = threadIdx.x >> 6, lane = threadIdx.x & 63;
    const int c = lane & 15, g = lane >> 4;
    // XCD swizzle: all 16 q-blocks of a head land on one XCD (1024 = 8 XCD * 128)
    const int bid = blockIdx.x;
    const int swz = (bid & 7) * 128 + (bid >> 3);
    const int bh = swz >> 4;
    const int qb = (swz & 15) * 128 + w * 32;
    const bf16* Qh = Qb + (size_t)bh * TT * 64;
    const bf16* Kh = Kb + (size_t)bh * TT * 64;
    const bf16* Vh = VT + (size_t)bh * 64 * TT;

    bf16x8 aq[2][2];
#pragma unroll
    for (int s = 0; s < 2; s++)
#pragma unroll
        for (int dt = 0; dt < 2; dt++)
            aq[s][dt] = *reinterpret_cast<const bf16x8*>(Qh + (size_t)(qb + 16 * s + c) * 64 + 32 * dt + 8 * g);

    // B-fragment of ones in column 0 only: row-sum collector
    bf16x8 onesf;
#pragma unroll
    for (int j = 0; j < 8; j++) onesf[j] = (c == 0) ? (bf16)1.0f : (bf16)0.0f;

    // prologue: K[0], V[0] loads; S[0]; K[1] loads
    bf16x8 kf[8];  // [kg*2+dt]
    bf16x8 vf[8];  // [dg*2+kt]
#pragma unroll
    for (int kg = 0; kg < 4; kg++)
#pragma unroll
        for (int dt = 0; dt < 2; dt++)
            kf[kg * 2 + dt] = *reinterpret_cast<const bf16x8*>(Kh + (size_t)(16 * kg + c) * 64 + 32 * dt + 8 * g);
#pragma unroll
    for (int dg = 0; dg < 4; dg++)
#pragma unroll
        for (int kt = 0; kt < 2; kt++)
            vf[dg * 2 + kt] = *reinterpret_cast<const bf16x8*>(Vh + (size_t)(16 * dg + c) * TT + 32 * kt + 8 * g);

    f32x4 o[2][4];
    f32x4 lacc[2];
#pragma unroll
    for (int s = 0; s < 2; s++) {
#pragma unroll
        for (int dg = 0; dg < 4; dg++)
#pragma unroll
            for (int r = 0; r < 4; r++) o[s][dg][r] = 0.0f;
#pragma unroll
        for (int r = 0; r < 4; r++) lacc[s][r] = 0.0f;
    }

    f32x4 sfA[2][4], sfB[2][4];
#pragma unroll
    for (int s = 0; s < 2; s++)
#pragma unroll
        for (int kg = 0; kg < 4; kg++)
#pragma unroll
            for (int r = 0; r < 4; r++) sfA[s][kg][r] = 0.0f;
#pragma unroll
    for (int kg = 0; kg < 4; kg++)
#pragma unroll
        for (int dt = 0; dt < 2; dt++)
#pragma unroll
            for (int s = 0; s < 2; s++)
                sfA[s][kg] = MFMA16(aq[s][dt], kf[kg * 2 + dt], sfA[s][kg]);
#pragma unroll
    for (int kg = 0; kg < 4; kg++)
#pragma unroll
        for (int dt = 0; dt < 2; dt++)
            kf[kg * 2 + dt] = *reinterpret_cast<const bf16x8*>(Kh + (size_t)(64 + 16 * kg + c) * 64 + 32 * dt + 8 * g);

    bf16* pl0 = plds[w][0];
    bf16* pl1 = plds[w][1];

    for (int tt = 0; tt < 16; tt++) {
        const int t0 = 2 * tt;
        ATTN_STEP(sfA, sfB, pl0, t0);
        ATTN_STEP(sfB, sfA, pl1, t0 + 1);
    }

    // l lives in lanes c==0 (col 0 of lacc); broadcast within each 16-lane group
    float linv[2][4];
#pragma unroll
    for (int s = 0; s < 2; s++)
#pragma unroll
        for (int r = 0; r < 4; r++) {
            float l = __shfl(lacc[s][r], lane & 48);
            linv[s][r] = 1.0f / l;
        }
#pragma unroll
    for (int s = 0; s < 2; s++)
#pragma unroll
        for (int dg = 0; dg < 4; dg++)
#pragma unroll
            for (int r = 0; r < 4; r++) {
                int tq = qb + 16 * s + 4 * g + r;
                AO[((size_t)bh * TT + tq) * 64 + 16 * dg + c] = (bf16)(o[s][dg][r] * linv[s][r]);
            }
}

// ---------------- Kernel 3: output projection (XCD-swizzled 1D grid) ----------------
// bid&7 selects the Wout column-slice AND the XCD (hw round-robin) -> slice L2-resident
__global__ __launch_bounds__(256) void k_oproj(const bf16* __restrict__ AO,
                                               const bf16* __restrict__ Wo,
                                               float* __restrict__ out) {
    const int w = threadIdx.x >> 6, lane = threadIdx.x & 63;
    const int c = lane & 15, g = lane >> 4;
    const int bid = blockIdx.x;
    const int nb = (bid & 7) * 128;
    const int mb = (bid >> 3) * 128 + w * 32;
    const int b = mb >> 11;
    const int t0 = mb & 2047;

    f32x4 acc[2][8];
#pragma unroll
    for (int s = 0; s < 2; s++)
#pragma unroll
        for (int ng = 0; ng < 8; ng++)
#pragma unroll
            for (int r = 0; r < 4; r++) acc[s][ng][r] = 0.0f;

    for (int kt = 0; kt < 32; kt++) {
        const int h = kt >> 1;
        bf16x8 aa[2];
#pragma unroll
        for (int s = 0; s < 2; s++)
            aa[s] = *reinterpret_cast<const bf16x8*>(
                AO + ((size_t)(b * HH + h) * TT + t0 + 16 * s + c) * 64 + 32 * (kt & 1) + 8 * g);
#pragma unroll
        for (int ng = 0; ng < 8; ng++) {
            bf16x8 bb = *reinterpret_cast<const bf16x8*>(Wo + (size_t)(nb + 16 * ng + c) * DD + 32 * kt + 8 * g);
#pragma unroll
            for (int s = 0; s < 2; s++)
                acc[s][ng] = MFMA16(aa[s], bb, acc[s][ng]);
        }
    }
#pragma unroll
    for (int s = 0; s < 2; s++)
#pragma unroll
        for (int ng = 0; ng < 8; ng++)
#pragma unroll
            for (int r = 0; r < 4; r++)
                out[(size_t)(mb + 16 * s + 4 * g + r) * DD + nb + 16 * ng + c] = acc[s][ng][r];
}

extern "C" void kernel_launch(void* const* d_in, const int* in_sizes, int n_in,
                              void* d_out, int out_size, void* d_ws, size_t ws_size,
                              hipStream_t stream) {
    const float* x = (const float*)d_in[0];
    const float* Wq = (const float*)d_in[1];
    const float* Wk = (const float*)d_in[2];
    const float* Wv = (const float*)d_in[3];
    const float* Wo = (const float*)d_in[4];
    float* out = (float*)d_out;

    char* ws = (char*)d_ws;
    bf16* Qb = (bf16*)(ws);                         // 16 MiB
    bf16* Kb = (bf16*)(ws + (16ll << 20));          // 16 MiB
    bf16* VT = (bf16*)(ws + (32ll << 20));          // 16 MiB
    bf16* AO = (bf16*)(ws + (48ll << 20));          // 16 MiB
    bf16* Wob = (bf16*)(ws + (64ll << 20));         // 2 MiB

    k_cvt<<<1024, 256, 0, stream>>>(Wo, Wob, DD * DD);
    k_qkv<<<dim3(TT / 128, BB * HH), 256, 0, stream>>>(x, Wq, Wk, Wv, Qb, Kb, VT);
    k_attn<<<1024, 256, 0, stream>>>(Qb, Kb, VT, AO);
    k_oproj<<<512, 256, 0, stream>>>(AO, Wob, out);
}

// Round 5
// 221.366 us; speedup vs baseline: 1.6265x; 1.6265x over previous
//
#include <hip/hip_runtime.h>
#include <hip/hip_bf16.h>

#define BB 4
#define TT 2048
#define DD 1024
#define HH 16

typedef __bf16 bf16;
typedef __bf16 bf16x8 __attribute__((ext_vector_type(8)));
typedef __bf16 bf16x4 __attribute__((ext_vector_type(4)));
typedef float f32x4 __attribute__((ext_vector_type(4)));
typedef unsigned int u32;

#define MFMA16(a, b, c) __builtin_amdgcn_mfma_f32_16x16x32_bf16(a, b, c, 0, 0, 0)

// softmax scale folded into Q at projection: (1/sqrt(64)) * log2(e)
#define C1 0.18033688011112042f

typedef __attribute__((address_space(1))) const u32 gau32;
typedef __attribute__((address_space(3))) u32 lau32;
static __device__ __forceinline__ void gload_lds16(const void* g, void* l) {
    __builtin_amdgcn_global_load_lds((gau32*)g, (lau32*)l, 16, 0, 0);
}

static __device__ inline bf16x8 cvt8(const float* __restrict__ p) {
    const f32x4 a = *reinterpret_cast<const f32x4*>(p);
    const f32x4 b = *reinterpret_cast<const f32x4*>(p + 4);
    bf16x8 r;
    r[0] = (bf16)a[0]; r[1] = (bf16)a[1]; r[2] = (bf16)a[2]; r[3] = (bf16)a[3];
    r[4] = (bf16)b[0]; r[5] = (bf16)b[1]; r[6] = (bf16)b[2]; r[7] = (bf16)b[3];
    return r;
}

// ---------------- Kernel 0: Wout fp32 -> bf16 ----------------
__global__ __launch_bounds__(256) void k_cvt(const float* __restrict__ a, bf16* __restrict__ o, int n) {
    int i = (blockIdx.x * 256 + threadIdx.x) * 4;
    if (i + 3 < n) {
        f32x4 v = *reinterpret_cast<const f32x4*>(a + i);
        bf16x4 r;
        r[0] = (bf16)v[0]; r[1] = (bf16)v[1]; r[2] = (bf16)v[2]; r[3] = (bf16)v[3];
        *reinterpret_cast<bf16x4*>(o + i) = r;
    }
}

// ---------------- Kernel 1: QKV projection ----------------
// Q (pre-scaled by C1), K -> (B*H, T, 64) bf16 ; V -> transposed (B*H, 64, T) bf16
__global__ __launch_bounds__(256) void k_qkv(const float* __restrict__ x,
                                             const float* __restrict__ Wq,
                                             const float* __restrict__ Wk,
                                             const float* __restrict__ Wv,
                                             bf16* __restrict__ Qb,
                                             bf16* __restrict__ Kb,
                                             bf16* __restrict__ VT) {
    __shared__ bf16 vlds[4][64 * 40];
    const int w = threadIdx.x >> 6, lane = threadIdx.x & 63;
    const int c = lane & 15, g = lane >> 4;
    const int bh = blockIdx.y;
    const int b = bh >> 4, h = bh & 15;
    const int tb = blockIdx.x * 128 + w * 32;

    bf16x8 a[2][2];
#pragma unroll
    for (int s = 0; s < 2; s++)
#pragma unroll
        for (int dt = 0; dt < 2; dt++)
            a[s][dt] = cvt8(x + (size_t)(b * TT + tb + 16 * s + c) * DD + h * 64 + 32 * dt + 8 * g);

    const float* const Ws[3] = {Wq, Wk, Wv};
    f32x4 acc[3][2][4];
#pragma unroll
    for (int m = 0; m < 3; m++)
#pragma unroll
        for (int s = 0; s < 2; s++)
#pragma unroll
            for (int e = 0; e < 4; e++)
#pragma unroll
                for (int r = 0; r < 4; r++) acc[m][s][e][r] = 0.0f;

#pragma unroll
    for (int m = 0; m < 3; m++) {
#pragma unroll
        for (int eg = 0; eg < 4; eg++) {
#pragma unroll
            for (int dt = 0; dt < 2; dt++) {
                bf16x8 bf = cvt8(Ws[m] + (size_t)(h * 64 + 16 * eg + c) * 64 + 32 * dt + 8 * g);
#pragma unroll
                for (int s = 0; s < 2; s++)
                    acc[m][s][eg] = MFMA16(a[s][dt], bf, acc[m][s][eg]);
            }
        }
    }

    bf16* const outs[2] = {Qb, Kb};
#pragma unroll
    for (int m = 0; m < 2; m++)
#pragma unroll
        for (int s = 0; s < 2; s++)
#pragma unroll
            for (int eg = 0; eg < 4; eg++)
#pragma unroll
                for (int r = 0; r < 4; r++) {
                    int t = tb + 16 * s + 4 * g + r;
                    float sv = acc[m][s][eg][r];
                    if (m == 0) sv *= C1;
                    outs[m][((size_t)bh * TT + t) * 64 + 16 * eg + c] = (bf16)sv;
                }

    // V: transpose via per-wave LDS tile [64 e][40 t_local]
    bf16* vl = vlds[w];
#pragma unroll
    for (int s = 0; s < 2; s++)
#pragma unroll
        for (int eg = 0; eg < 4; eg++) {
            bf16x4 v4;
#pragma unroll
            for (int r = 0; r < 4; r++) v4[r] = (bf16)acc[2][s][eg][r];
            *reinterpret_cast<bf16x4*>(&vl[(16 * eg + c) * 40 + 16 * s + 4 * g]) = v4;
        }
#pragma unroll
    for (int j = 0; j < 4; j++) {
        bf16x8 v = *reinterpret_cast<bf16x8*>(&vl[lane * 40 + 8 * j]);
        *reinterpret_cast<bf16x8*>(&VT[((size_t)bh * 64 + lane) * TT + tb + 8 * j]) = v;
    }
}

// ---------------- Kernel 2: flash attention (block-cooperative LDS staging) ----------------
// 512 blocks x 8 waves (2 blocks/CU). Per tile: K,V (64x64 bf16 each) staged once per
// block into XOR-swizzled LDS via global_load_lds(16B), double-buffered, 1 barrier/tile.
// Max-free softmax (exp2 direct, scale pre-folded into Q); row-sum via MFMA with ones-col.
__global__ __launch_bounds__(512, 4) void k_attn(const bf16* __restrict__ Qb,
                                                 const bf16* __restrict__ Kb,
                                                 const bf16* __restrict__ VT,
                                                 bf16* __restrict__ AO) {
    __shared__ bf16 sK[2][64 * 64];
    __shared__ bf16 sV[2][64 * 64];
    __shared__ bf16 plds[8][32 * 64];
    const int w = threadIdx.x >> 6, lane = threadIdx.x & 63;
    const int c = lane & 15, g = lane >> 4;
    // XCD swizzle: 8 heads (64 blocks) per XCD -> K/V L2-resident per XCD
    const int bid = blockIdx.x;
    const int swz = (bid & 7) * 64 + (bid >> 3);
    const int bh = swz >> 3;
    const int qb = (swz & 7) * 256 + w * 32;
    const bf16* Qh = Qb + (size_t)bh * TT * 64;
    const bf16* Kh = Kb + (size_t)bh * TT * 64;
    const bf16* Vh = VT + (size_t)bh * 64 * TT;

    // staging geometry: wave w stages chunk w (8 rows x 128B) of each tile
    const int srow = w * 8 + (lane >> 3);                       // 0..63
    const int scb = ((lane & 7) * 16) ^ ((srow & 7) << 4);      // swizzled byte col
    const bf16* kgsrc = Kh + (size_t)srow * 64 + (scb >> 1);    // + kb*64 per tile
    const bf16* vgsrc = Vh + (size_t)srow * TT + (scb >> 1);    // + kb per tile

    // prologue: stage tile 0 into buf 0
    gload_lds16(kgsrc, &sK[0][w * 512]);
    gload_lds16(vgsrc, &sV[0][w * 512]);

    bf16x8 aq[2][2];
#pragma unroll
    for (int s = 0; s < 2; s++)
#pragma unroll
        for (int dt = 0; dt < 2; dt++)
            aq[s][dt] = *reinterpret_cast<const bf16x8*>(Qh + (size_t)(qb + 16 * s + c) * 64 + 32 * dt + 8 * g);

    // B-fragment of ones in column 0 only: row-sum collector
    bf16x8 onesf;
#pragma unroll
    for (int j = 0; j < 8; j++) onesf[j] = (c == 0) ? (bf16)1.0f : (bf16)0.0f;

    f32x4 o[2][4];
    f32x4 lacc[2];
#pragma unroll
    for (int s = 0; s < 2; s++) {
#pragma unroll
        for (int dg = 0; dg < 4; dg++)
#pragma unroll
            for (int r = 0; r < 4; r++) o[s][dg][r] = 0.0f;
#pragma unroll
        for (int r = 0; r < 4; r++) lacc[s][r] = 0.0f;
    }

    bf16* pl = plds[w];
    const int swk = (c & 7) << 4;  // byte-swizzle for K/V fragment reads (row&7 == c&7)
    const int swp = (c & 7) << 3;  // element-swizzle for P fragment reads

    __syncthreads();  // tile 0 staged (implies vmcnt(0) drain)

    int buf = 0;
    for (int t = 0; t < 32; t++) {
        // ---- stage tile t+1 into buf^1 (in flight under this tile's compute) ----
        if (t < 31) {
            const int kbn = (t + 1) * 64;
            gload_lds16(kgsrc + (size_t)kbn * 64, &sK[buf ^ 1][w * 512]);
            gload_lds16(vgsrc + kbn, &sV[buf ^ 1][w * 512]);
        }
        const bf16* sk = sK[buf];
        const bf16* sv = sV[buf];

        // ---- QK^T from LDS ----
        f32x4 sf[2][4];
#pragma unroll
        for (int s = 0; s < 2; s++)
#pragma unroll
            for (int kg = 0; kg < 4; kg++)
#pragma unroll
                for (int r = 0; r < 4; r++) sf[s][kg][r] = 0.0f;
#pragma unroll
        for (int kg = 0; kg < 4; kg++) {
            bf16x8 kf[2];
#pragma unroll
            for (int dt = 0; dt < 2; dt++)
                kf[dt] = *reinterpret_cast<const bf16x8*>(&sk[(16 * kg + c) * 64 + (((64 * dt + 16 * g) ^ swk) >> 1)]);
            __builtin_amdgcn_s_setprio(1);
#pragma unroll
            for (int dt = 0; dt < 2; dt++)
#pragma unroll
                for (int s = 0; s < 2; s++)
                    sf[s][kg] = MFMA16(aq[s][dt], kf[dt], sf[s][kg]);
            __builtin_amdgcn_s_setprio(0);
        }

        // ---- p = exp2(s) -> P-LDS (XOR-swizzled, stride 64) ----
#pragma unroll
        for (int s = 0; s < 2; s++)
#pragma unroll
            for (int kg = 0; kg < 4; kg++)
#pragma unroll
                for (int r = 0; r < 4; r++) {
                    const int prow = 16 * s + 4 * g + r;
                    pl[prow * 64 + ((16 * kg + c) ^ (((4 * g + r) & 7) << 3))] = (bf16)exp2f(sf[s][kg][r]);
                }

        // ---- PV + row-sum from LDS ----
#pragma unroll
        for (int kt = 0; kt < 2; kt++) {
            bf16x8 pa[2];
#pragma unroll
            for (int s = 0; s < 2; s++)
                pa[s] = *reinterpret_cast<const bf16x8*>(&pl[(16 * s + c) * 64 + ((32 * kt + 8 * g) ^ swp)]);
            __builtin_amdgcn_s_setprio(1);
#pragma unroll
            for (int dg = 0; dg < 4; dg++) {
                bf16x8 bv = *reinterpret_cast<const bf16x8*>(&sv[(16 * dg + c) * 64 + (((64 * kt + 16 * g) ^ swk) >> 1)]);
#pragma unroll
                for (int s = 0; s < 2; s++)
                    o[s][dg] = MFMA16(pa[s], bv, o[s][dg]);
            }
#pragma unroll
            for (int s = 0; s < 2; s++)
                lacc[s] = MFMA16(pa[s], onesf, lacc[s]);
            __builtin_amdgcn_s_setprio(0);
        }

        __syncthreads();  // staged tile t+1 arrived; all waves done with buf
        buf ^= 1;
    }

    // l lives in lanes c==0 (col 0 of lacc); broadcast within each 16-lane group
    float linv[2][4];
#pragma unroll
    for (int s = 0; s < 2; s++)
#pragma unroll
        for (int r = 0; r < 4; r++) {
            float l = __shfl(lacc[s][r], lane & 48);
            linv[s][r] = 1.0f / l;
        }
#pragma unroll
    for (int s = 0; s < 2; s++)
#pragma unroll
        for (int dg = 0; dg < 4; dg++)
#pragma unroll
            for (int r = 0; r < 4; r++) {
                int tq = qb + 16 * s + 4 * g + r;
                AO[((size_t)bh * TT + tq) * 64 + 16 * dg + c] = (bf16)(o[s][dg][r] * linv[s][r]);
            }
}

// ---------------- Kernel 3: output projection (XCD-swizzled 1D grid) ----------------
__global__ __launch_bounds__(256) void k_oproj(const bf16* __restrict__ AO,
                                               const bf16* __restrict__ Wo,
                                               float* __restrict__ out) {
    const int w = threadIdx.x >> 6, lane = threadIdx.x & 63;
    const int c = lane & 15, g = lane >> 4;
    const int bid = blockIdx.x;
    const int nb = (bid & 7) * 128;
    const int mb = (bid >> 3) * 128 + w * 32;
    const int b = mb >> 11;
    const int t0 = mb & 2047;

    f32x4 acc[2][8];
#pragma unroll
    for (int s = 0; s < 2; s++)
#pragma unroll
        for (int ng = 0; ng < 8; ng++)
#pragma unroll
            for (int r = 0; r < 4; r++) acc[s][ng][r] = 0.0f;

    for (int kt = 0; kt < 32; kt++) {
        const int h = kt >> 1;
        bf16x8 aa[2];
#pragma unroll
        for (int s = 0; s < 2; s++)
            aa[s] = *reinterpret_cast<const bf16x8*>(
                AO + ((size_t)(b * HH + h) * TT + t0 + 16 * s + c) * 64 + 32 * (kt & 1) + 8 * g);
#pragma unroll
        for (int ng = 0; ng < 8; ng++) {
            bf16x8 bb = *reinterpret_cast<const bf16x8*>(Wo + (size_t)(nb + 16 * ng + c) * DD + 32 * kt + 8 * g);
#pragma unroll
            for (int s = 0; s < 2; s++)
                acc[s][ng] = MFMA16(aa[s], bb, acc[s][ng]);
        }
    }
#pragma unroll
    for (int s = 0; s < 2; s++)
#pragma unroll
        for (int ng = 0; ng < 8; ng++)
#pragma unroll
            for (int r = 0; r < 4; r++)
                out[(size_t)(mb + 16 * s + 4 * g + r) * DD + nb + 16 * ng + c] = acc[s][ng][r];
}

extern "C" void kernel_launch(void* const* d_in, const int* in_sizes, int n_in,
                              void* d_out, int out_size, void* d_ws, size_t ws_size,
                              hipStream_t stream) {
    const float* x = (const float*)d_in[0];
    const float* Wq = (const float*)d_in[1];
    const float* Wk = (const float*)d_in[2];
    const float* Wv = (const float*)d_in[3];
    const float* Wo = (const float*)d_in[4];
    float* out = (float*)d_out;

    char* ws = (char*)d_ws;
    bf16* Qb = (bf16*)(ws);                         // 16 MiB
    bf16* Kb = (bf16*)(ws + (16ll << 20));          // 16 MiB
    bf16* VT = (bf16*)(ws + (32ll << 20));          // 16 MiB
    bf16* AO = (bf16*)(ws + (48ll << 20));          // 16 MiB
    bf16* Wob = (bf16*)(ws + (64ll << 20));         // 2 MiB

    k_cvt<<<1024, 256, 0, stream>>>(Wo, Wob, DD * DD);
    k_qkv<<<dim3(TT / 128, BB * HH), 256, 0, stream>>>(x, Wq, Wk, Wv, Qb, Kb, VT);
    k_attn<<<512, 512, 0, stream>>>(Qb, Kb, VT, AO);
    k_oproj<<<512, 256, 0, stream>>>(AO, Wob, out);
}